// Round 12
// baseline (227.024 us; speedup 1.0000x reference)
//
#include <hip/hip_runtime.h>
#include <stdint.h>

typedef unsigned short u16;
typedef short short8 __attribute__((ext_vector_type(8)));
typedef float f32x4 __attribute__((ext_vector_type(4)));
typedef float f32x16 __attribute__((ext_vector_type(16)));

#define DM    2048
#define NH    16
#define NKV   4
#define DH    128
#define TQKV  3072
#define NB    2
#define SEQL  2048
#define MROWS (NB * SEQL)      // 4096
#define QDIM  (NH * DH)        // 2048
#define KVDIM (NKV * DH)       // 512
// 1/sqrt(128) * log2(e): attention scores computed in log2 units (exp2 softmax)
#define QSCALE_L2E 0.1275174336f

#define MFMA16(a, b, c) __builtin_amdgcn_mfma_f32_16x16x32_bf16((a), (b), (c), 0, 0, 0)
#define MFMA32(a, b, c) __builtin_amdgcn_mfma_f32_32x32x16_bf16((a), (b), (c), 0, 0, 0)

__device__ __forceinline__ u16 f2bf(float f) {
  uint32_t u = __float_as_uint(f);
  u += 0x7fffu + ((u >> 16) & 1u);
  return (u16)(u >> 16);
}
__device__ __forceinline__ float bf2f(u16 h) {
  return __uint_as_float(((uint32_t)h) << 16);
}
__device__ __forceinline__ void gload16(const u16* g, u16* l) {
  __builtin_amdgcn_global_load_lds((__attribute__((address_space(1))) void*)(u16*)g,
                                   (__attribute__((address_space(3))) void*)l, 16, 0, 0);
}
__device__ __forceinline__ uint32_t cvtpk(float lo, float hi) {
  uint32_t r;
  asm("v_cvt_pk_bf16_f32 %0, %1, %2" : "=v"(r) : "v"(lo), "v"(hi));
  return r;
}
__device__ __forceinline__ void swapln(uint32_t& a, uint32_t& b) {
  asm volatile("v_permlane32_swap_b32 %0, %1" : "+v"(a), "+v"(b));
}

// ---------------- fused prep: f32->bf16 convert + 4 weight transposes ----------------
__global__ __launch_bounds__(256) void k_prep(const float* __restrict__ hin,
                                              const float* __restrict__ wq,
                                              const float* __restrict__ wk,
                                              const float* __restrict__ wvv,
                                              const float* __restrict__ wo,
                                              u16* __restrict__ h_bf,
                                              u16* __restrict__ Wt,
                                              u16* __restrict__ Wot) {
  __shared__ float t[32][33];
  const int bid = blockIdx.x;
  const int tid = threadIdx.x;
  if (bid < 8192) {
    const int i = (bid * 256 + tid) * 4;
    float4 v = *reinterpret_cast<const float4*>(hin + i);
    u16* d = h_bf + i;
    d[0] = f2bf(v.x); d[1] = f2bf(v.y); d[2] = f2bf(v.z); d[3] = f2bf(v.w);
    return;
  }
  const float* src; u16* dst; int N, rowOff, bx, by;
  if (bid < 12288)      { const int r = bid - 8192;  src = wq;  dst = Wt;  N = 2048; rowOff = 0;    bx = r & 63; by = r >> 6; }
  else if (bid < 13312) { const int r = bid - 12288; src = wk;  dst = Wt;  N = 512;  rowOff = 2048; bx = r & 15; by = r >> 4; }
  else if (bid < 14336) { const int r = bid - 13312; src = wvv; dst = Wt;  N = 512;  rowOff = 2560; bx = r & 15; by = r >> 4; }
  else                  { const int r = bid - 14336; src = wo;  dst = Wot; N = 2048; rowOff = 0;    bx = r & 63; by = r >> 6; }
  const int n0 = bx * 32, k0 = by * 32;
  const int tx = tid & 31, ty = tid >> 5;
#pragma unroll
  for (int i = ty; i < 32; i += 8)
    t[i][tx] = src[(size_t)(k0 + i) * N + (n0 + tx)];
  __syncthreads();
#pragma unroll
  for (int i = ty; i < 32; i += 8)
    dst[(size_t)(rowOff + n0 + i) * 2048 + (k0 + tx)] = f2bf(t[tx][i]);
}

// ---------------- tiled transpose bf16 [R][C] -> bf16 [C][R], batched over z ----------------
__global__ void k_transpose_bf16(const u16* __restrict__ src, u16* __restrict__ dst, int R, int C) {
  __shared__ u16 t[32][33];
  const size_t zoff = (size_t)blockIdx.z * R * C;
  const int c0 = blockIdx.x * 32, r0 = blockIdx.y * 32;
  const int tx = threadIdx.x, ty = threadIdx.y;
#pragma unroll
  for (int i = ty; i < 32; i += 8)
    t[i][tx] = src[zoff + (size_t)(r0 + i) * C + (c0 + tx)];
  __syncthreads();
#pragma unroll
  for (int i = ty; i < 32; i += 8)
    dst[zoff + (size_t)(c0 + i) * R + (r0 + tx)] = t[tx][i];
}

// ---------------- bf16 GEMM, 256x256 tile, m201 8-phase template ----------------
// C[M][N] = A[M][K] * Bt[N][K]^T. 512 thr = 8 waves (2M x 4N), wave tile 128x64,
// BK=64, dbuf LDS 128 KB split [buf][A/B][half(128 rows)][128x64]. Bank-floor XOR
// swizzle (slot ^= row&7 over the 8 16B-slots of each 128B row), applied on BOTH
// sides: pre-swizzled global_load_lds source + swizzled ds_read (rule #21; same
// derivation as the verified conflict-free attn K swizzle). 4 quadrant-phases per
// K-tile: {ds-read frags -> barrier -> setprio+16 MFMA -> setprio0 -> barrier};
// full next-tile prefetch (8 loads/thread) issued at phase 0, so the per-tile
// vmcnt(0) finds them landed (~600cy early) - loads in flight across barriers.
template <int OUTBF>
__global__ __launch_bounds__(512) void k_gemm8p(const u16* __restrict__ A, const u16* __restrict__ Bt,
                                                float* __restrict__ Cf, u16* __restrict__ Cb,
                                                int M, int N, int K) {
  __shared__ u16 lds[65536];   // [2 buf][2 mat][2 half][128*64]
  const int tid = threadIdx.x;
  const int m0 = blockIdx.x * 256, n0 = blockIdx.y * 256;
  const int wv = tid >> 6, ln = tid & 63;
  const int wm = wv >> 2, wn = wv & 3;
  const int lr = ln & 15, lg4 = ln >> 4, lr7 = lr & 7;

  // staging coords (2 chunks/thread/half): ck -> row = ck>>3, slotL = ck&7,
  // global slot = slotL ^ (row&7)
  const int sr0 = tid >> 3,         ss0 = ((tid & 7) ^ (sr0 & 7)) * 8;
  const int sr1 = (tid + 512) >> 3, ss1 = (((tid + 512) & 7) ^ (sr1 & 7)) * 8;

  auto stage = [&](int buf, int kt) {
#pragma unroll
    for (int mat = 0; mat < 2; ++mat) {
      const u16* gs = mat ? Bt : A;
      const int rb = mat ? n0 : m0;
#pragma unroll
      for (int hf = 0; hf < 2; ++hf) {
        u16* dst = &lds[((buf * 2 + mat) * 2 + hf) * 8192];
        gload16(gs + (size_t)(rb + hf * 128 + sr0) * K + kt * 64 + ss0, dst + tid * 8);
        gload16(gs + (size_t)(rb + hf * 128 + sr1) * K + kt * 64 + ss1, dst + (tid + 512) * 8);
      }
    }
  };

  f32x4 acc[8][4];
#pragma unroll
  for (int i = 0; i < 8; ++i)
#pragma unroll
    for (int j = 0; j < 4; ++j) acc[i][j] = (f32x4){0.f, 0.f, 0.f, 0.f};

  const int nk = K >> 6;
  stage(0, 0);

  const int bro = (wn & 1) * 64;     // B row offset within half
  for (int t = 0; t < nk; ++t) {
    const int buf = t & 1;
    const u16* Ah = &lds[((buf * 2 + 0) * 2 + wm) * 8192];
    const u16* Bh = &lds[((buf * 2 + 1) * 2 + (wn >> 1)) * 8192];
    short8 af[4][2], bf[2][2], bg[2][2];

    // ---- phase 0: quadrant (qm0, qn0): i 0..3, j 0..1 ----
    asm volatile("s_waitcnt vmcnt(0)" ::: "memory");
    __builtin_amdgcn_s_barrier();
    if (t + 1 < nk) stage(buf ^ 1, t + 1);
#pragma unroll
    for (int i = 0; i < 4; ++i)
#pragma unroll
      for (int kk = 0; kk < 2; ++kk)
        af[i][kk] = *reinterpret_cast<const short8*>(
            &Ah[(i * 16 + lr) * 64 + (((kk * 4 + lg4) ^ lr7)) * 8]);
#pragma unroll
    for (int j = 0; j < 2; ++j)
#pragma unroll
      for (int kk = 0; kk < 2; ++kk)
        bf[j][kk] = *reinterpret_cast<const short8*>(
            &Bh[(bro + j * 16 + lr) * 64 + (((kk * 4 + lg4) ^ lr7)) * 8]);
    __builtin_amdgcn_s_setprio(1);
#pragma unroll
    for (int i = 0; i < 4; ++i)
#pragma unroll
      for (int j = 0; j < 2; ++j)
#pragma unroll
        for (int kk = 0; kk < 2; ++kk)
          acc[i][j] = MFMA16(af[i][kk], bf[j][kk], acc[i][j]);
    __builtin_amdgcn_s_setprio(0);
    __builtin_amdgcn_s_barrier();

    // ---- phase 1: (qm0, qn1): j 2..3 ----
#pragma unroll
    for (int j = 0; j < 2; ++j)
#pragma unroll
      for (int kk = 0; kk < 2; ++kk)
        bg[j][kk] = *reinterpret_cast<const short8*>(
            &Bh[(bro + (2 + j) * 16 + lr) * 64 + (((kk * 4 + lg4) ^ lr7)) * 8]);
    __builtin_amdgcn_s_barrier();
    __builtin_amdgcn_s_setprio(1);
#pragma unroll
    for (int i = 0; i < 4; ++i)
#pragma unroll
      for (int j = 0; j < 2; ++j)
#pragma unroll
        for (int kk = 0; kk < 2; ++kk)
          acc[i][2 + j] = MFMA16(af[i][kk], bg[j][kk], acc[i][2 + j]);
    __builtin_amdgcn_s_setprio(0);
    __builtin_amdgcn_s_barrier();

    // ---- phase 2: (qm1, qn0): i 4..7 (af regs reused) ----
#pragma unroll
    for (int i = 0; i < 4; ++i)
#pragma unroll
      for (int kk = 0; kk < 2; ++kk)
        af[i][kk] = *reinterpret_cast<const short8*>(
            &Ah[((4 + i) * 16 + lr) * 64 + (((kk * 4 + lg4) ^ lr7)) * 8]);
    __builtin_amdgcn_s_barrier();
    __builtin_amdgcn_s_setprio(1);
#pragma unroll
    for (int i = 0; i < 4; ++i)
#pragma unroll
      for (int j = 0; j < 2; ++j)
#pragma unroll
        for (int kk = 0; kk < 2; ++kk)
          acc[4 + i][j] = MFMA16(af[i][kk], bf[j][kk], acc[4 + i][j]);
    __builtin_amdgcn_s_setprio(0);
    __builtin_amdgcn_s_barrier();

    // ---- phase 3: (qm1, qn1): all frags in regs ----
    __builtin_amdgcn_s_barrier();
    __builtin_amdgcn_s_setprio(1);
#pragma unroll
    for (int i = 0; i < 4; ++i)
#pragma unroll
      for (int j = 0; j < 2; ++j)
#pragma unroll
        for (int kk = 0; kk < 2; ++kk)
          acc[4 + i][2 + j] = MFMA16(af[i][kk], bg[j][kk], acc[4 + i][2 + j]);
    __builtin_amdgcn_s_setprio(0);
    __builtin_amdgcn_s_barrier();
  }

  // epilogue: C/D row = (lane>>4)*4 + reg, col = lane&15
  const int rg = lg4 * 4;
#pragma unroll
  for (int i = 0; i < 8; ++i)
#pragma unroll
    for (int j = 0; j < 4; ++j) {
      const int row = m0 + wm * 128 + i * 16 + rg;
      const int col = n0 + wn * 64 + j * 16 + lr;
#pragma unroll
      for (int q = 0; q < 4; ++q) {
        float v = acc[i][j][q];
        if (OUTBF) Cb[(size_t)(row + q) * N + col] = f2bf(v);
        else       Cf[(size_t)(row + q) * N + col] = v;
      }
    }
}

// ---------------- bf16 GEMM: C[M][N] = A[M][K] * Bt[N][K]^T (proven 128^2) ----------------
template <int OUTBF>
__global__ __launch_bounds__(256) void k_gemm_bt(const u16* __restrict__ A, const u16* __restrict__ Bt,
                                                 float* __restrict__ Cf, u16* __restrict__ Cb,
                                                 int M, int N, int K) {
  __shared__ u16 As[2][128 * 32];
  __shared__ u16 Bs[2][128 * 32];
  const int tid = threadIdx.x;
  const int m0 = blockIdx.x * 128;
  const int n0 = blockIdx.y * 128;
  const int r  = tid >> 2;
  const int c8 = (tid & 3) << 3;
  const u16* Ag0 = A  + (size_t)(m0 + r) * K + c8;
  const u16* Ag1 = A  + (size_t)(m0 + 64 + r) * K + c8;
  const u16* Bg0 = Bt + (size_t)(n0 + r) * K + c8;
  const u16* Bg1 = Bt + (size_t)(n0 + 64 + r) * K + c8;

  auto stage = [&](int buf, int kt) {
    const int kg = kt * 32;
    gload16(Ag0 + kg, &As[buf][tid * 8]);
    gload16(Ag1 + kg, &As[buf][2048 + tid * 8]);
    gload16(Bg0 + kg, &Bs[buf][tid * 8]);
    gload16(Bg1 + kg, &Bs[buf][2048 + tid * 8]);
  };

  f32x4 acc[4][4];
#pragma unroll
  for (int i = 0; i < 4; ++i)
#pragma unroll
    for (int j = 0; j < 4; ++j) acc[i][j] = (f32x4){0.f, 0.f, 0.f, 0.f};

  const int wv = tid >> 6, ln = tid & 63;
  const int wr = (wv >> 1) * 64, wc = (wv & 1) * 64;
  const int lr = ln & 15, lko = (ln >> 4) * 8;

  stage(0, 0);
  __syncthreads();

  const int nk = K >> 5;
  for (int kt = 0; kt < nk; ++kt) {
    const int cur = kt & 1;
    if (kt + 1 < nk) stage(cur ^ 1, kt + 1);
    short8 af[4], bf[4];
#pragma unroll
    for (int i = 0; i < 4; ++i)
      af[i] = *reinterpret_cast<const short8*>(&As[cur][(wr + i * 16 + lr) * 32 + lko]);
#pragma unroll
    for (int i = 0; i < 4; ++i)
      bf[i] = *reinterpret_cast<const short8*>(&Bs[cur][(wc + i * 16 + lr) * 32 + lko]);
#pragma unroll
    for (int i = 0; i < 4; ++i)
#pragma unroll
      for (int j = 0; j < 4; ++j)
        acc[i][j] = MFMA16(af[i], bf[j], acc[i][j]);
    __syncthreads();
  }

  const int rg = (ln >> 4) * 4;
#pragma unroll
  for (int i = 0; i < 4; ++i) {
#pragma unroll
    for (int j = 0; j < 4; ++j) {
      const int row = m0 + wr + i * 16 + rg;
      const int col = n0 + wc + j * 16 + lr;
#pragma unroll
      for (int q = 0; q < 4; ++q) {
        float v = acc[i][j][q];
        if (OUTBF) Cb[(size_t)(row + q) * N + col] = f2bf(v);
        else       Cf[(size_t)(row + q) * N + col] = v;
      }
    }
  }
}

// ---------------- depthwise causal conv1d + residual + route to Q/K/V ----------------
__global__ void k_conv_route(const u16* __restrict__ qkv, const float* __restrict__ cw,
                             u16* __restrict__ Qh, u16* __restrict__ Kh, u16* __restrict__ Vsd) {
  const int row = blockIdx.x;            // b*SEQL + s
  const int b = row >> 11, s = row & 2047;
  const int c = threadIdx.x * 8;         // 384 threads -> 3072 channels
  float x[4][8];
#pragma unroll
  for (int k = 0; k < 4; ++k) {
    const int sr = s + k - 3;
    if (sr < 0) {
#pragma unroll
      for (int j = 0; j < 8; ++j) x[k][j] = 0.f;
    } else {
      short8 v = *reinterpret_cast<const short8*>(&qkv[(size_t)(b * SEQL + sr) * TQKV + c]);
#pragma unroll
      for (int j = 0; j < 8; ++j) x[k][j] = bf2f((u16)v[j]);
    }
  }
  float o[8];
#pragma unroll
  for (int j = 0; j < 8; ++j) {
    float4 w4 = *reinterpret_cast<const float4*>(&cw[(c + j) * 4]);
    o[j] = x[3][j] + x[0][j] * w4.x + x[1][j] * w4.y + x[2][j] * w4.z + x[3][j] * w4.w;
  }
  short8 ov;
  if (c < QDIM) {
#pragma unroll
    for (int j = 0; j < 8; ++j) ov[j] = (short)f2bf(o[j] * QSCALE_L2E);
    const int h = c >> 7, d = c & 127;
    *reinterpret_cast<short8*>(&Qh[((size_t)(b * NH + h) * SEQL + s) * DH + d]) = ov;
  } else if (c < QDIM + KVDIM) {
#pragma unroll
    for (int j = 0; j < 8; ++j) ov[j] = (short)f2bf(o[j]);
    const int cc = c - QDIM;
    const int h = cc >> 7, d = cc & 127;
    *reinterpret_cast<short8*>(&Kh[((size_t)(b * NKV + h) * SEQL + s) * DH + d]) = ov;
  } else {
#pragma unroll
    for (int j = 0; j < 8; ++j) ov[j] = (short)f2bf(o[j]);
    const int cc = c - QDIM - KVDIM;
    const int h = cc >> 7, d = cc & 127;
    *reinterpret_cast<short8*>(&Vsd[((size_t)(b * NKV + h) * SEQL + s) * DH + d]) = ov;
  }
}

// ---------------- GQA causal flash attention: balanced split-KV + counted-vmcnt + bank-floor LDS ----------------
__global__ __launch_bounds__(512) void k_attn(const u16* __restrict__ Qh, const u16* __restrict__ Kh,
                                              const u16* __restrict__ Vt, u16* __restrict__ att,
                                              u16* __restrict__ pO, float* __restrict__ pm,
                                              float* __restrict__ pl) {
  static const int qbA_t[8] = {7,6,5,4,7,6,5,4};
  static const int tA0_t[8] = {0,0,0,0,18,18,18,18};
  static const int tA1_t[8] = {18,18,18,18,32,28,24,20};
  static const int chkA_t[8]= {0,0,0,0,1,1,1,1};
  static const int qbB_t[8] = {0,0,0,0,0,1,2,3};
  static const int tB1_t[8] = {0,0,0,0,4,8,12,16};

  const int slot = blockIdx.x >> 5;    // 0..7
  const int bh = blockIdx.x & 31;      // 0..31
  const int s = bh & 7, tt = bh >> 3;  // stream (XCD), head-in-group
  const int b = s >> 2, kvh = s & 3;
  const int h = kvh * 4 + tt;
  const int bhl = b * NH + h;

  __shared__ u16 Ks[3][64 * 128];
  __shared__ u16 Vs[3][128 * 64];
  const int tid = threadIdx.x, wv = tid >> 6, ln = tid & 63;
  const int lq = ln & 31, hi = ln >> 5;
  const int hi16 = hi * 16;
  const int swk = (lq & 15) << 4;      // K read swizzle (4-bit, slot*16 domain)

  const u16* kg = Kh + (size_t)(b * NKV + kvh) * SEQL * DH;
  const u16* vg = Vt + (size_t)(b * NKV + kvh) * DH * SEQL;

  const int ck0 = tid, ck1 = tid + 512;
  const int krow0 = ck0 >> 4, kcb0 = (ck0 & 15) << 4;
  const int krow1 = ck1 >> 4, kcb1 = (ck1 & 15) << 4;
  const int koff0 = krow0 * DH + ((kcb0 ^ ((krow0 & 15) << 4)) >> 1);
  const int koff1 = krow1 * DH + ((kcb1 ^ ((krow1 & 15) << 4)) >> 1);
  const int vline0 = ck0 >> 4, vslotG0 = (ck0 & 15) ^ (vline0 & 15);
  const int vline1 = ck1 >> 4, vslotG1 = (ck1 & 15) ^ (vline1 & 15);
  const int voff0 = (vline0 * 2 + (vslotG0 >> 3)) * SEQL + (vslotG0 & 7) * 8;
  const int voff1 = (vline1 * 2 + (vslotG1 >> 3)) * SEQL + (vslotG1 & 7) * 8;

  auto stage = [&](int buf, int kvs) {
    gload16(kg + (size_t)kvs * DH + koff0, &Ks[buf][ck0 * 8]);
    gload16(kg + (size_t)kvs * DH + koff1, &Ks[buf][ck1 * 8]);
    gload16(vg + (size_t)kvs + voff0, &Vs[buf][ck0 * 8]);
    gload16(vg + (size_t)kvs + voff1, &Vs[buf][ck1 * 8]);
  };

  for (int seg = 0; seg < 2; ++seg) {
    int qb, tA, tB, split, chk;
    if (seg == 0) {
      qb = qbA_t[slot]; tA = tA0_t[slot]; tB = tA1_t[slot]; split = 1; chk = chkA_t[slot];
    } else {
      tB = tB1_t[slot];
      if (tB == 0) break;
      qb = qbB_t[slot]; tA = 0; split = 0; chk = 0;
    }

    const int q0w = qb * 256 + wv * 32;
    const int qg = q0w + lq;

    const u16* qrow = Qh + ((size_t)(b * NH + h) * SEQL + qg) * DH;
    short8 qf[8];
#pragma unroll
    for (int dblk = 0; dblk < 8; ++dblk)
      qf[dblk] = *reinterpret_cast<const short8*>(qrow + dblk * 16 + hi * 8);

    f32x16 oacc[4];
#pragma unroll
    for (int nb = 0; nb < 4; ++nb)
#pragma unroll
      for (int rq = 0; rq < 16; ++rq) oacc[nb][rq] = 0.f;
    float mrow = -1e30f, lrow = 0.f;

    stage(0, tA * 64);
    if (tA + 1 < tB) stage(1, (tA + 1) * 64);
    int cur = 0;

    for (int t = tA; t < tB; ++t) {
      if (t + 1 < tB) { asm volatile("s_waitcnt vmcnt(4)" ::: "memory"); }
      else            { asm volatile("s_waitcnt vmcnt(0)" ::: "memory"); }
      __builtin_amdgcn_s_barrier();
      const int nxt = (cur == 2) ? 0 : cur + 1;
      const int nn  = (nxt == 2) ? 0 : nxt + 1;
      if (t + 2 < tB) stage(nn, (t + 2) * 64);
      const int kvs = t * 64;
      if (kvs <= q0w + 31) {
        const u16* ks = Ks[cur];
        const u16* vs = Vs[cur];
        f32x16 st[2];
#pragma unroll
        for (int kvb = 0; kvb < 2; ++kvb)
#pragma unroll
          for (int rq = 0; rq < 16; ++rq) st[kvb][rq] = 0.f;

        __builtin_amdgcn_s_setprio(1);
#pragma unroll
        for (int kvb = 0; kvb < 2; ++kvb) {
          const u16* krow = ks + (kvb * 32 + lq) * 128;
#pragma unroll
          for (int dblk = 0; dblk < 8; ++dblk) {
            short8 kf = *reinterpret_cast<const short8*>(krow + (((dblk * 32 + hi16) ^ swk) >> 1));
            st[kvb] = MFMA32(kf, qf[dblk], st[kvb]);
          }
        }
        __builtin_amdgcn_s_setprio(0);

        if (kvs + 63 > q0w) {
#pragma unroll
          for (int kvb = 0; kvb < 2; ++kvb)
#pragma unroll
            for (int rq = 0; rq < 16; ++rq) {
              const int kvg = kvs + kvb * 32 + (rq & 3) + 8 * (rq >> 2) + 4 * hi;
              if (kvg > qg) st[kvb][rq] = -1e30f;
            }
        }

        float a0 = st[0][0], a1 = st[0][1], a2 = st[0][2], a3 = st[0][3];
#pragma unroll
        for (int kvb = 0; kvb < 2; ++kvb)
#pragma unroll
          for (int rq = (kvb ? 0 : 4); rq < 16; rq += 4) {
            a0 = fmaxf(a0, st[kvb][rq]);
            a1 = fmaxf(a1, st[kvb][rq + 1]);
            a2 = fmaxf(a2, st[kvb][rq + 2]);
            a3 = fmaxf(a3, st[kvb][rq + 3]);
          }
        float tm = fmaxf(fmaxf(a0, a1), fmaxf(a2, a3));
        tm = fmaxf(tm, __shfl_xor(tm, 32));
        if (__any(tm > mrow + 11.0f)) {          // T13 defer-max (log2 units)
          const float nm = fmaxf(mrow, tm);
          const float scl = exp2f(mrow - nm);
          mrow = nm;
          lrow *= scl;
#pragma unroll
          for (int nb = 0; nb < 4; ++nb)
#pragma unroll
            for (int rq = 0; rq < 16; ++rq) oacc[nb][rq] *= scl;
        }
        float s0 = 0.f, s1 = 0.f, s2 = 0.f, s3 = 0.f;
#pragma unroll
        for (int kvb = 0; kvb < 2; ++kvb)
#pragma unroll
          for (int rq = 0; rq < 16; rq += 4) {
            float p0 = exp2f(st[kvb][rq] - mrow);
            float p1 = exp2f(st[kvb][rq + 1] - mrow);
            float p2 = exp2f(st[kvb][rq + 2] - mrow);
            float p3 = exp2f(st[kvb][rq + 3] - mrow);
            st[kvb][rq] = p0; st[kvb][rq + 1] = p1; st[kvb][rq + 2] = p2; st[kvb][rq + 3] = p3;
            s0 += p0; s1 += p1; s2 += p2; s3 += p3;
          }
        float ps = (s0 + s1) + (s2 + s3);
        ps += __shfl_xor(ps, 32);
        lrow += ps;

        uint32_t w[4][4];
#pragma unroll
        for (int kvb = 0; kvb < 2; ++kvb) {
          uint32_t x0 = cvtpk(st[kvb][0], st[kvb][1]);
          uint32_t y0 = cvtpk(st[kvb][4], st[kvb][5]);
          swapln(x0, y0);
          uint32_t x1 = cvtpk(st[kvb][2], st[kvb][3]);
          uint32_t y1 = cvtpk(st[kvb][6], st[kvb][7]);
          swapln(x1, y1);
          w[kvb * 2][0] = x0; w[kvb * 2][1] = x1; w[kvb * 2][2] = y0; w[kvb * 2][3] = y1;
          uint32_t x2 = cvtpk(st[kvb][8], st[kvb][9]);
          uint32_t y2 = cvtpk(st[kvb][12], st[kvb][13]);
          swapln(x2, y2);
          uint32_t x3 = cvtpk(st[kvb][10], st[kvb][11]);
          uint32_t y3 = cvtpk(st[kvb][14], st[kvb][15]);
          swapln(x3, y3);
          w[kvb * 2 + 1][0] = x2; w[kvb * 2 + 1][1] = x3; w[kvb * 2 + 1][2] = y2; w[kvb * 2 + 1][3] = y3;
        }
        short8 pa[4];
#pragma unroll
        for (int kc = 0; kc < 4; ++kc) {
          union { uint32_t uw[4]; short8 s; } pu;
#pragma unroll
          for (int j = 0; j < 4; ++j) pu.uw[j] = w[kc][j];
          pa[kc] = pu.s;
        }

        __builtin_amdgcn_s_setprio(1);
        const int vsw = lq >> 1;
        const int sbase = (lq & 1) << 3;
#pragma unroll
        for (int nb = 0; nb < 4; ++nb) {
          const u16* vline = vs + (nb * 16 + (lq >> 1)) * 128;
#pragma unroll
          for (int kc = 0; kc < 4; ++kc) {
            short8 vf = *reinterpret_cast<const short8*>(vline + (((sbase | (kc * 2 + hi)) ^ vsw) << 3));
            oacc[nb] = MFMA32(vf, pa[kc], oacc[nb]);
          }
        }
        __builtin_amdgcn_s_setprio(0);
      }
      cur = nxt;
    }

    if (!split) {
      const float inv = 1.0f / lrow;
      u16* orow = att + ((size_t)(b * SEQL + qg)) * QDIM + h * DH;
#pragma unroll
      for (int nb = 0; nb < 4; ++nb)
#pragma unroll
        for (int rg = 0; rg < 4; ++rg) {
          const int rq = rg * 4;
          uint2 vout;
          vout.x = cvtpk(oacc[nb][rq] * inv, oacc[nb][rq + 1] * inv);
          vout.y = cvtpk(oacc[nb][rq + 2] * inv, oacc[nb][rq + 3] * inv);
          *reinterpret_cast<uint2*>(orow + nb * 32 + 8 * rg + 4 * hi) = vout;
        }
    } else {
      const int rowp = ((bhl * 4 + (qb - 4)) << 8) + wv * 32 + lq;   // 0..32767
      u16* prow = pO + (size_t)chk * 32768 * 128 + (size_t)rowp * 128;
#pragma unroll
      for (int nb = 0; nb < 4; ++nb)
#pragma unroll
        for (int rg = 0; rg < 4; ++rg) {
          const int rq = rg * 4;
          uint2 vout;
          vout.x = cvtpk(oacc[nb][rq], oacc[nb][rq + 1]);
          vout.y = cvtpk(oacc[nb][rq + 2], oacc[nb][rq + 3]);
          *reinterpret_cast<uint2*>(prow + nb * 32 + 8 * rg + 4 * hi) = vout;
        }
      if (!hi) {
        pm[chk * 32768 + rowp] = mrow;
        pl[chk * 32768 + rowp] = lrow;
      }
    }
    __syncthreads();
  }
}

// ---------------- combine split-KV partials ----------------
__global__ void k_combine(const u16* __restrict__ pO, const float* __restrict__ pm,
                          const float* __restrict__ pl, u16* __restrict__ att) {
  const int e = blockIdx.x * 256 + threadIdx.x;    // 0..524287: 8 d-elems each
  const int rowp = e >> 4;
  const int d8 = (e & 15) * 8;
  const float m0 = pm[rowp], m1 = pm[32768 + rowp];
  const float l0 = pl[rowp], l1 = pl[32768 + rowp];
  const float mm = fmaxf(m0, m1);
  const float a0 = exp2f(m0 - mm), a1 = exp2f(m1 - mm);
  const float inv = 1.0f / (l0 * a0 + l1 * a1);
  const float w0 = a0 * inv, w1 = a1 * inv;
  short8 o0 = *reinterpret_cast<const short8*>(pO + (size_t)rowp * 128 + d8);
  short8 o1 = *reinterpret_cast<const short8*>(pO + (size_t)32768 * 128 + (size_t)rowp * 128 + d8);
  const int bh = rowp >> 10, qb = 4 + ((rowp >> 8) & 3), r = rowp & 255;
  const int b = bh >> 4, h = bh & 15;
  u16* orow = att + ((size_t)(b * SEQL + qb * 256 + r)) * QDIM + h * DH + d8;
  uint2 vout;
  float r0 = bf2f((u16)o0[0]) * w0 + bf2f((u16)o1[0]) * w1;
  float r1 = bf2f((u16)o0[1]) * w0 + bf2f((u16)o1[1]) * w1;
  float r2 = bf2f((u16)o0[2]) * w0 + bf2f((u16)o1[2]) * w1;
  float r3 = bf2f((u16)o0[3]) * w0 + bf2f((u16)o1[3]) * w1;
  float r4 = bf2f((u16)o0[4]) * w0 + bf2f((u16)o1[4]) * w1;
  float r5 = bf2f((u16)o0[5]) * w0 + bf2f((u16)o1[5]) * w1;
  float r6 = bf2f((u16)o0[6]) * w0 + bf2f((u16)o1[6]) * w1;
  float r7 = bf2f((u16)o0[7]) * w0 + bf2f((u16)o1[7]) * w1;
  vout.x = ((uint32_t)f2bf(r1) << 16) | f2bf(r0);
  vout.y = ((uint32_t)f2bf(r3) << 16) | f2bf(r2);
  uint2 vout2;
  vout2.x = ((uint32_t)f2bf(r5) << 16) | f2bf(r4);
  vout2.y = ((uint32_t)f2bf(r7) << 16) | f2bf(r6);
  *reinterpret_cast<uint2*>(orow) = vout;
  *reinterpret_cast<uint2*>(orow + 4) = vout2;
}

// ---------------- launch ----------------
extern "C" void kernel_launch(void* const* d_in, const int* in_sizes, int n_in,
                              void* d_out, int out_size, void* d_ws, size_t ws_size,
                              hipStream_t stream) {
  const float* hin = (const float*)d_in[0];
  const float* wq  = (const float*)d_in[1];
  const float* wk  = (const float*)d_in[2];
  const float* wvv = (const float*)d_in[3];
  const float* wo  = (const float*)d_in[4];
  const float* cw  = (const float*)d_in[5];
  float* out = (float*)d_out;
  char* ws = (char*)d_ws;

  u16* h_bf = (u16*)(ws + 0);                       // 16,777,216  [4096][2048]
  u16* Wt   = (u16*)(ws + 16777216);                // 12,582,912  [3072][2048]
  u16* Wot  = (u16*)(ws + 29360128);                //  8,388,608  [2048][2048]
  u16* Qh   = (u16*)(ws + 37748736);                // 16,777,216  [B][NH][S][DH]
  u16* Kh   = (u16*)(ws + 54525952);                //  4,194,304  [B][NKV][S][DH]
  u16* Vsd  = (u16*)(ws + 58720256);                //  4,194,304  [B][NKV][S][DH]
  u16* Vt   = (u16*)(ws + 62914560);                //  4,194,304  [B][NKV][DH][S]
  u16* att  = (u16*)(ws + 67108864);                // 16,777,216  [4096][2048]
  u16* qkv  = (u16*)d_out;                          // scratch reuse (dead after conv)
  u16*   pO = (u16*)d_out;                          // [2][32768][128] bf16 = 16.78 MB
  float* pm = (float*)((char*)d_out + 16777216);    // [2][32768] f32
  float* pl = (float*)((char*)d_out + 16777216 + 262144);

  dim3 tb(32, 8);
  k_prep<<<dim3(18432), 256, 0, stream>>>(hin, wq, wk, wvv, wo, h_bf, Wt, Wot);
  k_gemm8p<1><<<dim3(16, 12), 512, 0, stream>>>(h_bf, Wt, nullptr, qkv, MROWS, TQKV, DM);
  k_conv_route<<<MROWS, 384, 0, stream>>>(qkv, cw, Qh, Kh, Vsd);
  k_transpose_bf16<<<dim3(4, 64, NB * NKV), tb, 0, stream>>>(Vsd, Vt, SEQL, DH);
  k_attn<<<dim3(256), 512, 0, stream>>>(Qh, Kh, Vt, att, pO, pm, pl);
  k_combine<<<dim3(2048), 256, 0, stream>>>(pO, pm, pl, att);
  k_gemm_bt<0><<<dim3(32, 16), 256, 0, stream>>>(att, Wot, out, nullptr, MROWS, DM, DM);
}

// Round 13
// 217.780 us; speedup vs baseline: 1.0424x; 1.0424x over previous
//
#include <hip/hip_runtime.h>
#include <stdint.h>

typedef unsigned short u16;
typedef short short8 __attribute__((ext_vector_type(8)));
typedef float f32x4 __attribute__((ext_vector_type(4)));
typedef float f32x16 __attribute__((ext_vector_type(16)));

#define DM    2048
#define NH    16
#define NKV   4
#define DH    128
#define TQKV  3072
#define NB    2
#define SEQL  2048
#define MROWS (NB * SEQL)      // 4096
#define QDIM  (NH * DH)        // 2048
#define KVDIM (NKV * DH)       // 512
// 1/sqrt(128) * log2(e): attention scores computed in log2 units (exp2 softmax)
#define QSCALE_L2E 0.1275174336f

#define MFMA16(a, b, c) __builtin_amdgcn_mfma_f32_16x16x32_bf16((a), (b), (c), 0, 0, 0)
#define MFMA32(a, b, c) __builtin_amdgcn_mfma_f32_32x32x16_bf16((a), (b), (c), 0, 0, 0)

__device__ __forceinline__ u16 f2bf(float f) {
  uint32_t u = __float_as_uint(f);
  u += 0x7fffu + ((u >> 16) & 1u);
  return (u16)(u >> 16);
}
__device__ __forceinline__ float bf2f(u16 h) {
  return __uint_as_float(((uint32_t)h) << 16);
}
__device__ __forceinline__ void gload16(const u16* g, u16* l) {
  __builtin_amdgcn_global_load_lds((__attribute__((address_space(1))) void*)(u16*)g,
                                   (__attribute__((address_space(3))) void*)l, 16, 0, 0);
}
__device__ __forceinline__ uint32_t cvtpk(float lo, float hi) {
  uint32_t r;
  asm("v_cvt_pk_bf16_f32 %0, %1, %2" : "=v"(r) : "v"(lo), "v"(hi));
  return r;
}
__device__ __forceinline__ void swapln(uint32_t& a, uint32_t& b) {
  asm volatile("v_permlane32_swap_b32 %0, %1" : "+v"(a), "+v"(b));
}

// ---------------- fused prep: f32->bf16 convert + 4 weight transposes ----------------
__global__ __launch_bounds__(256) void k_prep(const float* __restrict__ hin,
                                              const float* __restrict__ wq,
                                              const float* __restrict__ wk,
                                              const float* __restrict__ wvv,
                                              const float* __restrict__ wo,
                                              u16* __restrict__ h_bf,
                                              u16* __restrict__ Wt,
                                              u16* __restrict__ Wot) {
  __shared__ float t[32][33];
  const int bid = blockIdx.x;
  const int tid = threadIdx.x;
  if (bid < 8192) {
    const int i = (bid * 256 + tid) * 4;
    float4 v = *reinterpret_cast<const float4*>(hin + i);
    u16* d = h_bf + i;
    d[0] = f2bf(v.x); d[1] = f2bf(v.y); d[2] = f2bf(v.z); d[3] = f2bf(v.w);
    return;
  }
  const float* src; u16* dst; int N, rowOff, bx, by;
  if (bid < 12288)      { const int r = bid - 8192;  src = wq;  dst = Wt;  N = 2048; rowOff = 0;    bx = r & 63; by = r >> 6; }
  else if (bid < 13312) { const int r = bid - 12288; src = wk;  dst = Wt;  N = 512;  rowOff = 2048; bx = r & 15; by = r >> 4; }
  else if (bid < 14336) { const int r = bid - 13312; src = wvv; dst = Wt;  N = 512;  rowOff = 2560; bx = r & 15; by = r >> 4; }
  else                  { const int r = bid - 14336; src = wo;  dst = Wot; N = 2048; rowOff = 0;    bx = r & 63; by = r >> 6; }
  const int n0 = bx * 32, k0 = by * 32;
  const int tx = tid & 31, ty = tid >> 5;
#pragma unroll
  for (int i = ty; i < 32; i += 8)
    t[i][tx] = src[(size_t)(k0 + i) * N + (n0 + tx)];
  __syncthreads();
#pragma unroll
  for (int i = ty; i < 32; i += 8)
    dst[(size_t)(rowOff + n0 + i) * 2048 + (k0 + tx)] = f2bf(t[tx][i]);
}

// ---------------- bf16 GEMM: C[M][N] = A[M][K] * Bt[N][K]^T (proven 128^2) ----------------
template <int OUTBF>
__global__ __launch_bounds__(256) void k_gemm_bt(const u16* __restrict__ A, const u16* __restrict__ Bt,
                                                 float* __restrict__ Cf, u16* __restrict__ Cb,
                                                 int M, int N, int K) {
  __shared__ u16 As[2][128 * 32];
  __shared__ u16 Bs[2][128 * 32];
  const int tid = threadIdx.x;
  const int m0 = blockIdx.x * 128;
  const int n0 = blockIdx.y * 128;
  const int r  = tid >> 2;
  const int c8 = (tid & 3) << 3;
  const u16* Ag0 = A  + (size_t)(m0 + r) * K + c8;
  const u16* Ag1 = A  + (size_t)(m0 + 64 + r) * K + c8;
  const u16* Bg0 = Bt + (size_t)(n0 + r) * K + c8;
  const u16* Bg1 = Bt + (size_t)(n0 + 64 + r) * K + c8;

  auto stage = [&](int buf, int kt) {
    const int kg = kt * 32;
    gload16(Ag0 + kg, &As[buf][tid * 8]);
    gload16(Ag1 + kg, &As[buf][2048 + tid * 8]);
    gload16(Bg0 + kg, &Bs[buf][tid * 8]);
    gload16(Bg1 + kg, &Bs[buf][2048 + tid * 8]);
  };

  f32x4 acc[4][4];
#pragma unroll
  for (int i = 0; i < 4; ++i)
#pragma unroll
    for (int j = 0; j < 4; ++j) acc[i][j] = (f32x4){0.f, 0.f, 0.f, 0.f};

  const int wv = tid >> 6, ln = tid & 63;
  const int wr = (wv >> 1) * 64, wc = (wv & 1) * 64;
  const int lr = ln & 15, lko = (ln >> 4) * 8;

  stage(0, 0);
  __syncthreads();

  const int nk = K >> 5;
  for (int kt = 0; kt < nk; ++kt) {
    const int cur = kt & 1;
    if (kt + 1 < nk) stage(cur ^ 1, kt + 1);
    short8 af[4], bf[4];
#pragma unroll
    for (int i = 0; i < 4; ++i)
      af[i] = *reinterpret_cast<const short8*>(&As[cur][(wr + i * 16 + lr) * 32 + lko]);
#pragma unroll
    for (int i = 0; i < 4; ++i)
      bf[i] = *reinterpret_cast<const short8*>(&Bs[cur][(wc + i * 16 + lr) * 32 + lko]);
#pragma unroll
    for (int i = 0; i < 4; ++i)
#pragma unroll
      for (int j = 0; j < 4; ++j)
        acc[i][j] = MFMA16(af[i], bf[j], acc[i][j]);
    __syncthreads();
  }

  const int rg = (ln >> 4) * 4;
#pragma unroll
  for (int i = 0; i < 4; ++i) {
#pragma unroll
    for (int j = 0; j < 4; ++j) {
      const int row = m0 + wr + i * 16 + rg;
      const int col = n0 + wc + j * 16 + lr;
#pragma unroll
      for (int q = 0; q < 4; ++q) {
        float v = acc[i][j][q];
        if (OUTBF) Cb[(size_t)(row + q) * N + col] = f2bf(v);
        else       Cf[(size_t)(row + q) * N + col] = v;
      }
    }
  }
}

// ---------------- fused depthwise causal conv1d + residual + route + V-transpose ----------------
// Blocks 0..4095: one (b,s) row, threads 0..319 handle Q/K channels 0..2559.
// Blocks 4096..4607: V tiles (b, kvh, 32-s-tile): conv computed independently from
// qkv (rows s-3..s only - no cross-block dependency) and stored TRANSPOSED into
// Vt[d][s] with coalesced 64B segments (wave = 2 d-groups x 32 consecutive s).
__global__ __launch_bounds__(512) void k_conv_route(const u16* __restrict__ qkv, const float* __restrict__ cw,
                                                    u16* __restrict__ Qh, u16* __restrict__ Kh,
                                                    u16* __restrict__ Vt) {
  if (blockIdx.x < 4096) {
    const int row = blockIdx.x;          // b*SEQL + s
    if (threadIdx.x >= 320) return;
    const int b = row >> 11, s = row & 2047;
    const int c = threadIdx.x * 8;       // 0..2552
    float x[4][8];
#pragma unroll
    for (int k = 0; k < 4; ++k) {
      const int sr = s + k - 3;
      if (sr < 0) {
#pragma unroll
        for (int j = 0; j < 8; ++j) x[k][j] = 0.f;
      } else {
        short8 v = *reinterpret_cast<const short8*>(&qkv[(size_t)(b * SEQL + sr) * TQKV + c]);
#pragma unroll
        for (int j = 0; j < 8; ++j) x[k][j] = bf2f((u16)v[j]);
      }
    }
    float o[8];
#pragma unroll
    for (int j = 0; j < 8; ++j) {
      float4 w4 = *reinterpret_cast<const float4*>(&cw[(c + j) * 4]);
      o[j] = x[3][j] + x[0][j] * w4.x + x[1][j] * w4.y + x[2][j] * w4.z + x[3][j] * w4.w;
    }
    short8 ov;
    if (c < QDIM) {
#pragma unroll
      for (int j = 0; j < 8; ++j) ov[j] = (short)f2bf(o[j] * QSCALE_L2E);
      const int h = c >> 7, d = c & 127;
      *reinterpret_cast<short8*>(&Qh[((size_t)(b * NH + h) * SEQL + s) * DH + d]) = ov;
    } else {
#pragma unroll
      for (int j = 0; j < 8; ++j) ov[j] = (short)f2bf(o[j]);
      const int cc = c - QDIM;
      const int h = cc >> 7, d = cc & 127;
      *reinterpret_cast<short8*>(&Kh[((size_t)(b * NKV + h) * SEQL + s) * DH + d]) = ov;
    }
  } else {
    // V conv + transpose: vb -> (b, kvh, s-tile)
    const int vb = blockIdx.x - 4096;    // 0..511
    const int b = vb >> 8;
    const int kvh = (vb >> 6) & 3;
    const int st = vb & 63;
    const int d8 = threadIdx.x >> 5;     // 0..15
    const int ss = threadIdx.x & 31;
    const int s = st * 32 + ss;
    const int c = QDIM + KVDIM + kvh * 128 + d8 * 8;
    float x[4][8];
#pragma unroll
    for (int k = 0; k < 4; ++k) {
      const int sr = s + k - 3;
      if (sr < 0) {
#pragma unroll
        for (int j = 0; j < 8; ++j) x[k][j] = 0.f;
      } else {
        short8 v = *reinterpret_cast<const short8*>(&qkv[(size_t)(b * SEQL + sr) * TQKV + c]);
#pragma unroll
        for (int j = 0; j < 8; ++j) x[k][j] = bf2f((u16)v[j]);
      }
    }
    u16* vtb = Vt + (size_t)(b * NKV + kvh) * DH * SEQL;
#pragma unroll
    for (int j = 0; j < 8; ++j) {
      float4 w4 = *reinterpret_cast<const float4*>(&cw[(c + j) * 4]);
      float o = x[3][j] + x[0][j] * w4.x + x[1][j] * w4.y + x[2][j] * w4.z + x[3][j] * w4.w;
      vtb[(size_t)(d8 * 8 + j) * SEQL + s] = f2bf(o);
    }
  }
}

// ---------------- GQA causal flash attention: balanced split-KV + counted-vmcnt + bank-floor LDS ----------------
__global__ __launch_bounds__(512) void k_attn(const u16* __restrict__ Qh, const u16* __restrict__ Kh,
                                              const u16* __restrict__ Vt, u16* __restrict__ att,
                                              u16* __restrict__ pO, float* __restrict__ pm,
                                              float* __restrict__ pl) {
  static const int qbA_t[8] = {7,6,5,4,7,6,5,4};
  static const int tA0_t[8] = {0,0,0,0,18,18,18,18};
  static const int tA1_t[8] = {18,18,18,18,32,28,24,20};
  static const int chkA_t[8]= {0,0,0,0,1,1,1,1};
  static const int qbB_t[8] = {0,0,0,0,0,1,2,3};
  static const int tB1_t[8] = {0,0,0,0,4,8,12,16};

  const int slot = blockIdx.x >> 5;    // 0..7
  const int bh = blockIdx.x & 31;      // 0..31
  const int s = bh & 7, tt = bh >> 3;  // stream (XCD), head-in-group
  const int b = s >> 2, kvh = s & 3;
  const int h = kvh * 4 + tt;
  const int bhl = b * NH + h;

  __shared__ u16 Ks[3][64 * 128];
  __shared__ u16 Vs[3][128 * 64];
  const int tid = threadIdx.x, wv = tid >> 6, ln = tid & 63;
  const int lq = ln & 31, hi = ln >> 5;
  const int hi16 = hi * 16;
  const int swk = (lq & 15) << 4;      // K read swizzle (4-bit, slot*16 domain)

  const u16* kg = Kh + (size_t)(b * NKV + kvh) * SEQL * DH;
  const u16* vg = Vt + (size_t)(b * NKV + kvh) * DH * SEQL;

  const int ck0 = tid, ck1 = tid + 512;
  const int krow0 = ck0 >> 4, kcb0 = (ck0 & 15) << 4;
  const int krow1 = ck1 >> 4, kcb1 = (ck1 & 15) << 4;
  const int koff0 = krow0 * DH + ((kcb0 ^ ((krow0 & 15) << 4)) >> 1);
  const int koff1 = krow1 * DH + ((kcb1 ^ ((krow1 & 15) << 4)) >> 1);
  const int vline0 = ck0 >> 4, vslotG0 = (ck0 & 15) ^ (vline0 & 15);
  const int vline1 = ck1 >> 4, vslotG1 = (ck1 & 15) ^ (vline1 & 15);
  const int voff0 = (vline0 * 2 + (vslotG0 >> 3)) * SEQL + (vslotG0 & 7) * 8;
  const int voff1 = (vline1 * 2 + (vslotG1 >> 3)) * SEQL + (vslotG1 & 7) * 8;

  auto stage = [&](int buf, int kvs) {
    gload16(kg + (size_t)kvs * DH + koff0, &Ks[buf][ck0 * 8]);
    gload16(kg + (size_t)kvs * DH + koff1, &Ks[buf][ck1 * 8]);
    gload16(vg + (size_t)kvs + voff0, &Vs[buf][ck0 * 8]);
    gload16(vg + (size_t)kvs + voff1, &Vs[buf][ck1 * 8]);
  };

  for (int seg = 0; seg < 2; ++seg) {
    int qb, tA, tB, split, chk;
    if (seg == 0) {
      qb = qbA_t[slot]; tA = tA0_t[slot]; tB = tA1_t[slot]; split = 1; chk = chkA_t[slot];
    } else {
      tB = tB1_t[slot];
      if (tB == 0) break;
      qb = qbB_t[slot]; tA = 0; split = 0; chk = 0;
    }

    const int q0w = qb * 256 + wv * 32;
    const int qg = q0w + lq;

    const u16* qrow = Qh + ((size_t)(b * NH + h) * SEQL + qg) * DH;
    short8 qf[8];
#pragma unroll
    for (int dblk = 0; dblk < 8; ++dblk)
      qf[dblk] = *reinterpret_cast<const short8*>(qrow + dblk * 16 + hi * 8);

    f32x16 oacc[4];
#pragma unroll
    for (int nb = 0; nb < 4; ++nb)
#pragma unroll
      for (int rq = 0; rq < 16; ++rq) oacc[nb][rq] = 0.f;
    float mrow = -1e30f, lrow = 0.f;

    stage(0, tA * 64);
    if (tA + 1 < tB) stage(1, (tA + 1) * 64);
    int cur = 0;

    for (int t = tA; t < tB; ++t) {
      if (t + 1 < tB) { asm volatile("s_waitcnt vmcnt(4)" ::: "memory"); }
      else            { asm volatile("s_waitcnt vmcnt(0)" ::: "memory"); }
      __builtin_amdgcn_s_barrier();
      const int nxt = (cur == 2) ? 0 : cur + 1;
      const int nn  = (nxt == 2) ? 0 : nxt + 1;
      if (t + 2 < tB) stage(nn, (t + 2) * 64);
      const int kvs = t * 64;
      if (kvs <= q0w + 31) {
        const u16* ks = Ks[cur];
        const u16* vs = Vs[cur];
        f32x16 st[2];
#pragma unroll
        for (int kvb = 0; kvb < 2; ++kvb)
#pragma unroll
          for (int rq = 0; rq < 16; ++rq) st[kvb][rq] = 0.f;

        __builtin_amdgcn_s_setprio(1);
#pragma unroll
        for (int kvb = 0; kvb < 2; ++kvb) {
          const u16* krow = ks + (kvb * 32 + lq) * 128;
#pragma unroll
          for (int dblk = 0; dblk < 8; ++dblk) {
            short8 kf = *reinterpret_cast<const short8*>(krow + (((dblk * 32 + hi16) ^ swk) >> 1));
            st[kvb] = MFMA32(kf, qf[dblk], st[kvb]);
          }
        }
        __builtin_amdgcn_s_setprio(0);

        if (kvs + 63 > q0w) {
#pragma unroll
          for (int kvb = 0; kvb < 2; ++kvb)
#pragma unroll
            for (int rq = 0; rq < 16; ++rq) {
              const int kvg = kvs + kvb * 32 + (rq & 3) + 8 * (rq >> 2) + 4 * hi;
              if (kvg > qg) st[kvb][rq] = -1e30f;
            }
        }

        float a0 = st[0][0], a1 = st[0][1], a2 = st[0][2], a3 = st[0][3];
#pragma unroll
        for (int kvb = 0; kvb < 2; ++kvb)
#pragma unroll
          for (int rq = (kvb ? 0 : 4); rq < 16; rq += 4) {
            a0 = fmaxf(a0, st[kvb][rq]);
            a1 = fmaxf(a1, st[kvb][rq + 1]);
            a2 = fmaxf(a2, st[kvb][rq + 2]);
            a3 = fmaxf(a3, st[kvb][rq + 3]);
          }
        float tm = fmaxf(fmaxf(a0, a1), fmaxf(a2, a3));
        tm = fmaxf(tm, __shfl_xor(tm, 32));
        if (__any(tm > mrow + 11.0f)) {          // T13 defer-max (log2 units)
          const float nm = fmaxf(mrow, tm);
          const float scl = exp2f(mrow - nm);
          mrow = nm;
          lrow *= scl;
#pragma unroll
          for (int nb = 0; nb < 4; ++nb)
#pragma unroll
            for (int rq = 0; rq < 16; ++rq) oacc[nb][rq] *= scl;
        }
        float s0 = 0.f, s1 = 0.f, s2 = 0.f, s3 = 0.f;
#pragma unroll
        for (int kvb = 0; kvb < 2; ++kvb)
#pragma unroll
          for (int rq = 0; rq < 16; rq += 4) {
            float p0 = exp2f(st[kvb][rq] - mrow);
            float p1 = exp2f(st[kvb][rq + 1] - mrow);
            float p2 = exp2f(st[kvb][rq + 2] - mrow);
            float p3 = exp2f(st[kvb][rq + 3] - mrow);
            st[kvb][rq] = p0; st[kvb][rq + 1] = p1; st[kvb][rq + 2] = p2; st[kvb][rq + 3] = p3;
            s0 += p0; s1 += p1; s2 += p2; s3 += p3;
          }
        float ps = (s0 + s1) + (s2 + s3);
        ps += __shfl_xor(ps, 32);
        lrow += ps;

        uint32_t w[4][4];
#pragma unroll
        for (int kvb = 0; kvb < 2; ++kvb) {
          uint32_t x0 = cvtpk(st[kvb][0], st[kvb][1]);
          uint32_t y0 = cvtpk(st[kvb][4], st[kvb][5]);
          swapln(x0, y0);
          uint32_t x1 = cvtpk(st[kvb][2], st[kvb][3]);
          uint32_t y1 = cvtpk(st[kvb][6], st[kvb][7]);
          swapln(x1, y1);
          w[kvb * 2][0] = x0; w[kvb * 2][1] = x1; w[kvb * 2][2] = y0; w[kvb * 2][3] = y1;
          uint32_t x2 = cvtpk(st[kvb][8], st[kvb][9]);
          uint32_t y2 = cvtpk(st[kvb][12], st[kvb][13]);
          swapln(x2, y2);
          uint32_t x3 = cvtpk(st[kvb][10], st[kvb][11]);
          uint32_t y3 = cvtpk(st[kvb][14], st[kvb][15]);
          swapln(x3, y3);
          w[kvb * 2 + 1][0] = x2; w[kvb * 2 + 1][1] = x3; w[kvb * 2 + 1][2] = y2; w[kvb * 2 + 1][3] = y3;
        }
        short8 pa[4];
#pragma unroll
        for (int kc = 0; kc < 4; ++kc) {
          union { uint32_t uw[4]; short8 s; } pu;
#pragma unroll
          for (int j = 0; j < 4; ++j) pu.uw[j] = w[kc][j];
          pa[kc] = pu.s;
        }

        __builtin_amdgcn_s_setprio(1);
        const int vsw = lq >> 1;
        const int sbase = (lq & 1) << 3;
#pragma unroll
        for (int nb = 0; nb < 4; ++nb) {
          const u16* vline = vs + (nb * 16 + (lq >> 1)) * 128;
#pragma unroll
          for (int kc = 0; kc < 4; ++kc) {
            short8 vf = *reinterpret_cast<const short8*>(vline + (((sbase | (kc * 2 + hi)) ^ vsw) << 3));
            oacc[nb] = MFMA32(vf, pa[kc], oacc[nb]);
          }
        }
        __builtin_amdgcn_s_setprio(0);
      }
      cur = nxt;
    }

    if (!split) {
      const float inv = 1.0f / lrow;
      u16* orow = att + ((size_t)(b * SEQL + qg)) * QDIM + h * DH;
#pragma unroll
      for (int nb = 0; nb < 4; ++nb)
#pragma unroll
        for (int rg = 0; rg < 4; ++rg) {
          const int rq = rg * 4;
          uint2 vout;
          vout.x = cvtpk(oacc[nb][rq] * inv, oacc[nb][rq + 1] * inv);
          vout.y = cvtpk(oacc[nb][rq + 2] * inv, oacc[nb][rq + 3] * inv);
          *reinterpret_cast<uint2*>(orow + nb * 32 + 8 * rg + 4 * hi) = vout;
        }
    } else {
      const int rowp = ((bhl * 4 + (qb - 4)) << 8) + wv * 32 + lq;   // 0..32767
      u16* prow = pO + (size_t)chk * 32768 * 128 + (size_t)rowp * 128;
#pragma unroll
      for (int nb = 0; nb < 4; ++nb)
#pragma unroll
        for (int rg = 0; rg < 4; ++rg) {
          const int rq = rg * 4;
          uint2 vout;
          vout.x = cvtpk(oacc[nb][rq], oacc[nb][rq + 1]);
          vout.y = cvtpk(oacc[nb][rq + 2], oacc[nb][rq + 3]);
          *reinterpret_cast<uint2*>(prow + nb * 32 + 8 * rg + 4 * hi) = vout;
        }
      if (!hi) {
        pm[chk * 32768 + rowp] = mrow;
        pl[chk * 32768 + rowp] = lrow;
      }
    }
    __syncthreads();
  }
}

// ---------------- combine split-KV partials ----------------
__global__ void k_combine(const u16* __restrict__ pO, const float* __restrict__ pm,
                          const float* __restrict__ pl, u16* __restrict__ att) {
  const int e = blockIdx.x * 256 + threadIdx.x;    // 0..524287: 8 d-elems each
  const int rowp = e >> 4;
  const int d8 = (e & 15) * 8;
  const float m0 = pm[rowp], m1 = pm[32768 + rowp];
  const float l0 = pl[rowp], l1 = pl[32768 + rowp];
  const float mm = fmaxf(m0, m1);
  const float a0 = exp2f(m0 - mm), a1 = exp2f(m1 - mm);
  const float inv = 1.0f / (l0 * a0 + l1 * a1);
  const float w0 = a0 * inv, w1 = a1 * inv;
  short8 o0 = *reinterpret_cast<const short8*>(pO + (size_t)rowp * 128 + d8);
  short8 o1 = *reinterpret_cast<const short8*>(pO + (size_t)32768 * 128 + (size_t)rowp * 128 + d8);
  const int bh = rowp >> 10, qb = 4 + ((rowp >> 8) & 3), r = rowp & 255;
  const int b = bh >> 4, h = bh & 15;
  u16* orow = att + ((size_t)(b * SEQL + qb * 256 + r)) * QDIM + h * DH + d8;
  uint2 vout;
  float r0 = bf2f((u16)o0[0]) * w0 + bf2f((u16)o1[0]) * w1;
  float r1 = bf2f((u16)o0[1]) * w0 + bf2f((u16)o1[1]) * w1;
  float r2 = bf2f((u16)o0[2]) * w0 + bf2f((u16)o1[2]) * w1;
  float r3 = bf2f((u16)o0[3]) * w0 + bf2f((u16)o1[3]) * w1;
  float r4 = bf2f((u16)o0[4]) * w0 + bf2f((u16)o1[4]) * w1;
  float r5 = bf2f((u16)o0[5]) * w0 + bf2f((u16)o1[5]) * w1;
  float r6 = bf2f((u16)o0[6]) * w0 + bf2f((u16)o1[6]) * w1;
  float r7 = bf2f((u16)o0[7]) * w0 + bf2f((u16)o1[7]) * w1;
  vout.x = ((uint32_t)f2bf(r1) << 16) | f2bf(r0);
  vout.y = ((uint32_t)f2bf(r3) << 16) | f2bf(r2);
  uint2 vout2;
  vout2.x = ((uint32_t)f2bf(r5) << 16) | f2bf(r4);
  vout2.y = ((uint32_t)f2bf(r7) << 16) | f2bf(r6);
  *reinterpret_cast<uint2*>(orow) = vout;
  *reinterpret_cast<uint2*>(orow + 4) = vout2;
}

// ---------------- launch ----------------
extern "C" void kernel_launch(void* const* d_in, const int* in_sizes, int n_in,
                              void* d_out, int out_size, void* d_ws, size_t ws_size,
                              hipStream_t stream) {
  const float* hin = (const float*)d_in[0];
  const float* wq  = (const float*)d_in[1];
  const float* wk  = (const float*)d_in[2];
  const float* wvv = (const float*)d_in[3];
  const float* wo  = (const float*)d_in[4];
  const float* cw  = (const float*)d_in[5];
  float* out = (float*)d_out;
  char* ws = (char*)d_ws;

  u16* h_bf = (u16*)(ws + 0);                       // 16,777,216  [4096][2048]
  u16* Wt   = (u16*)(ws + 16777216);                // 12,582,912  [3072][2048]
  u16* Wot  = (u16*)(ws + 29360128);                //  8,388,608  [2048][2048]
  u16* Qh   = (u16*)(ws + 37748736);                // 16,777,216  [B][NH][S][DH]
  u16* Kh   = (u16*)(ws + 54525952);                //  4,194,304  [B][NKV][S][DH]
  u16* Vt   = (u16*)(ws + 62914560);                //  4,194,304  [B][NKV][DH][S]
  u16* att  = (u16*)(ws + 67108864);                // 16,777,216  [4096][2048]
  u16* qkv  = (u16*)d_out;                          // scratch reuse (dead after conv)
  u16*   pO = (u16*)d_out;                          // [2][32768][128] bf16 = 16.78 MB
  float* pm = (float*)((char*)d_out + 16777216);    // [2][32768] f32
  float* pl = (float*)((char*)d_out + 16777216 + 262144);

  k_prep<<<dim3(18432), 256, 0, stream>>>(hin, wq, wk, wvv, wo, h_bf, Wt, Wot);
  k_gemm_bt<1><<<dim3(32, 24), 256, 0, stream>>>(h_bf, Wt, nullptr, qkv, MROWS, TQKV, DM);
  k_conv_route<<<dim3(4608), 512, 0, stream>>>(qkv, cw, Qh, Kh, Vt);
  k_attn<<<dim3(256), 512, 0, stream>>>(Qh, Kh, Vt, att, pO, pm, pl);
  k_combine<<<dim3(2048), 256, 0, stream>>>(pO, pm, pl, att);
  k_gemm_bt<0><<<dim3(32, 16), 256, 0, stream>>>(att, Wot, out, nullptr, MROWS, DM, DM);
}